// Round 21
// baseline (396.662 us; speedup 1.0000x reference)
//
#include <hip/hip_runtime.h>
#include <cstdint>

typedef unsigned short u16;
typedef unsigned int u32;
typedef __bf16 bf16x8 __attribute__((ext_vector_type(8)));
typedef float f32x4 __attribute__((ext_vector_type(4)));

#define DEVINL __device__ __forceinline__

DEVINL float bf2f(u16 h) { union { u32 u; float f; } v; v.u = ((u32)h) << 16; return v.f; }
DEVINL u16 f2bf(float f) {
  union { __bf16 h; u16 u; } v;
  v.h = (__bf16)f;  // native cvt (RNE); pairs into v_cvt_pk_bf16_f32
  return v.u;
}

DEVINL float fexp2(float x) {
#if __has_builtin(__builtin_amdgcn_exp2f)
  return __builtin_amdgcn_exp2f(x);
#else
  return exp2f(x);
#endif
}

// async global->LDS, 16B per lane. LDS dest must be wave-uniform base + lane*16.
DEVINL void gld_lds16(const void* g, void* l) {
  __builtin_amdgcn_global_load_lds(
      (__attribute__((address_space(1))) void*)(g),
      (__attribute__((address_space(3))) void*)(l), 16, 0, 0);
}

// ---------------- merged prep: LN1 (blocks 0..8191) + 6 weight transposes ---
__global__ __launch_bounds__(256) void kprep(
    const float* __restrict__ x, const float* __restrict__ Wq,
    const float* __restrict__ Wk, const float* __restrict__ Wv,
    const float* __restrict__ Wp, const float* __restrict__ W1,
    const float* __restrict__ W2, const float* __restrict__ g,
    const float* __restrict__ be, u16* __restrict__ x1,
    u16* __restrict__ wqkvT, u16* __restrict__ wpT,
    u16* __restrict__ w1T, u16* __restrict__ w2T) {
  int b = blockIdx.x;
  int t = threadIdx.x;
  if (b < 8192) {  // ---- LN1 row b (fp32 input) ----
    long row = b;
    float4 xv = *(const float4*)&x[row * 1024 + t * 4];
    float f0 = xv.x, f1 = xv.y, f2 = xv.z, f3 = xv.w;
    float s = f0 + f1 + f2 + f3;
    float s2 = f0 * f0 + f1 * f1 + f2 * f2 + f3 * f3;
#pragma unroll
    for (int off = 32; off >= 1; off >>= 1) {
      s += __shfl_xor(s, off);
      s2 += __shfl_xor(s2, off);
    }
    __shared__ float red[8];
    int w = t >> 6, l = t & 63;
    if (l == 0) { red[w] = s; red[4 + w] = s2; }
    __syncthreads();
    s = red[0] + red[1] + red[2] + red[3];
    s2 = red[4] + red[5] + red[6] + red[7];
    float mu = s * (1.0f / 1024.0f);
    float var = s2 * (1.0f / 1024.0f) - mu * mu;
    float rs = rsqrtf(var + 1e-5f);
    float4 gv = *(const float4*)&g[t * 4];
    float4 bv = *(const float4*)&be[t * 4];
    ushort4 ov;
    ov.x = f2bf((f0 - mu) * rs * gv.x + bv.x);
    ov.y = f2bf((f1 - mu) * rs * gv.y + bv.y);
    ov.z = f2bf((f2 - mu) * rs * gv.z + bv.z);
    ov.w = f2bf((f3 - mu) * rs * gv.w + bv.w);
    *(ushort4*)&x1[row * 1024 + t * 4] = ov;
    return;
  }
  int jb = b - 8192;
  const float* in;
  u16* out;
  int R, C, c0, r0;
  if (jb < 768) {
    int which = jb >> 8;
    int idx = jb & 255;
    int z = idx >> 4, y = idx & 15;
    const float* W = (which == 0) ? Wq : ((which == 1) ? Wk : Wv);
    in = W + (long)z * 65536;
    out = wqkvT + (long)which * 1048576 + (long)z * 65536;
    R = 1024; C = 64; c0 = 0; r0 = y * 64;
  } else if (jb < 1024) {
    int idx = jb - 768;
    in = Wp; out = wpT; R = 1024; C = 1024;
    c0 = (idx & 15) * 64; r0 = (idx >> 4) * 64;
  } else if (jb < 2048) {
    int idx = jb - 1024;
    in = W1; out = w1T; R = 1024; C = 4096;
    c0 = (idx & 63) * 64; r0 = (idx >> 6) * 64;
  } else {
    int idx = jb - 2048;
    in = W2; out = w2T; R = 4096; C = 1024;
    c0 = (idx & 15) * 64; r0 = (idx >> 4) * 64;
  }
  __shared__ __align__(16) u16 tile[64][80];
#pragma unroll
  for (int ph = 0; ph < 2; ++ph) {
    int ch = ph * 256 + t;
    int r = ch >> 3, cc = (ch & 7) * 8;
    const float* src = &in[(long)(r0 + r) * C + c0 + cc];
    float4 a = *(const float4*)src;
    float4 bb = *(const float4*)(src + 4);
    u16 tmp[8] = {f2bf(a.x), f2bf(a.y), f2bf(a.z), f2bf(a.w),
                  f2bf(bb.x), f2bf(bb.y), f2bf(bb.z), f2bf(bb.w)};
    *(uint4*)&tile[r][cc] = *(uint4*)tmp;
  }
  __syncthreads();
#pragma unroll
  for (int ph = 0; ph < 2; ++ph) {
    int ch = ph * 256 + t;
    int c = ch >> 3, rr = (ch & 7) * 8;
    u16 tmp[8];
#pragma unroll
    for (int i = 0; i < 8; ++i) tmp[i] = tile[rr + i][c];
    *(uint4*)&out[(long)(c0 + c) * R + r0 + rr] = *(uint4*)tmp;
  }
}

// -------- LayerNorm rows of 1024, bf16 input --------------------------------
__global__ __launch_bounds__(256) void kln_b(const u16* __restrict__ x,
                                             const float* __restrict__ g,
                                             const float* __restrict__ be,
                                             u16* __restrict__ y) {
  long row = blockIdx.x;
  int t = threadIdx.x;
  ushort4 xv = *(const ushort4*)&x[row * 1024 + t * 4];
  float f0 = bf2f(xv.x), f1 = bf2f(xv.y), f2 = bf2f(xv.z), f3 = bf2f(xv.w);
  float s = f0 + f1 + f2 + f3;
  float s2 = f0 * f0 + f1 * f1 + f2 * f2 + f3 * f3;
#pragma unroll
  for (int off = 32; off >= 1; off >>= 1) {
    s += __shfl_xor(s, off);
    s2 += __shfl_xor(s2, off);
  }
  __shared__ float red[8];
  int w = t >> 6, l = t & 63;
  if (l == 0) { red[w] = s; red[4 + w] = s2; }
  __syncthreads();
  s = red[0] + red[1] + red[2] + red[3];
  s2 = red[4] + red[5] + red[6] + red[7];
  float mu = s * (1.0f / 1024.0f);
  float var = s2 * (1.0f / 1024.0f) - mu * mu;
  float rs = rsqrtf(var + 1e-5f);
  float4 gv = *(const float4*)&g[t * 4];
  float4 bv = *(const float4*)&be[t * 4];
  ushort4 ov;
  ov.x = f2bf((f0 - mu) * rs * gv.x + bv.x);
  ov.y = f2bf((f1 - mu) * rs * gv.y + bv.y);
  ov.z = f2bf((f2 - mu) * rs * gv.z + bv.z);
  ov.w = f2bf((f3 - mu) * rs * gv.w + bv.w);
  *(ushort4*)&y[row * 1024 + t * 4] = ov;
}

// ---------------- GEMM (r17 proven 128x128 structure + XCD swizzle) ---------
template <int EPI, int OF32>
__global__ __launch_bounds__(256) void kgemm(const u16* __restrict__ A,
                                             const u16* __restrict__ BT, int K,
                                             const float* __restrict__ bias,
                                             const u16* __restrict__ resid,
                                             void* __restrict__ outv, int ldc,
                                             u16* __restrict__ vout) {
  __shared__ __align__(16) u16 sA[128 * 64];
  __shared__ __align__(16) u16 sB[128 * 64];
  int tid = threadIdx.x;
  int l = tid & 63, wv = tid >> 6;
  int wm = (wv >> 1) * 64, wn = (wv & 1) * 64;
  int flat = blockIdx.y * gridDim.x + blockIdx.x;
  int cpx = (gridDim.x * gridDim.y) >> 3;
  int lg = (flat & 7) * cpx + (flat >> 3);
  int bx = lg % gridDim.x, by = lg / gridDim.x;
  long m0 = (long)by * 128, n0 = (long)bx * 128;
  const u16* Ab = A + m0 * K;
  const u16* Bb = BT + n0 * K;
  f32x4 acc[4][4] = {};

  for (int k0 = 0; k0 < K; k0 += 64) {
    __syncthreads();
#pragma unroll
    for (int it = 0; it < 4; ++it) {
      int c = it * 256 + tid;
      int r = c >> 3;
      int k8 = (c & 7) ^ (r & 7);
      gld_lds16(Ab + (long)r * K + k0 + k8 * 8, &sA[c * 8]);
    }
#pragma unroll
    for (int it = 0; it < 4; ++it) {
      int c = it * 256 + tid;
      int r = c >> 3;
      int k8 = (c & 7) ^ (r & 7);
      gld_lds16(Bb + (long)r * K + k0 + k8 * 8, &sB[c * 8]);
    }
    __syncthreads();
#pragma unroll
    for (int kk = 0; kk < 2; ++kk) {
      int k8 = kk * 4 + (l >> 4);
      bf16x8 af[4], bfr[4];
#pragma unroll
      for (int mi = 0; mi < 4; ++mi) {
        int r = wm + mi * 16 + (l & 15);
        af[mi] = *(const bf16x8*)&sA[(r * 8 + (k8 ^ (r & 7))) * 8];
      }
#pragma unroll
      for (int ni = 0; ni < 4; ++ni) {
        int r = wn + ni * 16 + (l & 15);
        bfr[ni] = *(const bf16x8*)&sB[(r * 8 + (k8 ^ (r & 7))) * 8];
      }
#pragma unroll
      for (int mi = 0; mi < 4; ++mi)
#pragma unroll
        for (int ni = 0; ni < 4; ++ni)
          acc[mi][ni] =
              __builtin_amdgcn_mfma_f32_16x16x32_bf16(af[mi], bfr[ni], acc[mi][ni], 0, 0, 0);
    }
  }
#pragma unroll
  for (int mi = 0; mi < 4; ++mi) {
#pragma unroll
    for (int ni = 0; ni < 4; ++ni) {
#pragma unroll
      for (int j = 0; j < 4; ++j) {
        long row = m0 + wm + mi * 16 + (l >> 4) * 4 + j;
        long col = n0 + wn + ni * 16 + (l & 15);
        float v = acc[mi][ni][j];
        if constexpr (EPI == 0) {
          long tn = col >> 10, jj = col & 1023;
          long hh = jj >> 6, dd = jj & 63;
          long bb = row >> 11, tt = row & 2047;
          if (tn == 0) {
            v *= 0.045084220027780106f;  // log2(e)/32: exp2 domain
            ((u16*)outv)[(((bb)*16 + hh) * 2048 + tt) * 64 + dd] = f2bf(v);
          } else if (tn == 1) {
            ((u16*)outv)[(((4 + bb) * 16 + hh) * 2048 + tt) * 64 + dd] = f2bf(v);
          } else {  // V: write directly transposed [bh][d][T]
            vout[((bb * 16 + hh) * 64 + dd) * 2048 + tt] = f2bf(v);
          }
        } else {
          v += bias[col];
          if constexpr (EPI == 2) v = fmaxf(v, 0.0f);
          if constexpr (EPI == 1) v += bf2f(resid[row * ldc + col]);
          if constexpr (OF32) ((float*)outv)[row * ldc + col] = v;
          else ((u16*)outv)[row * ldc + col] = f2bf(v);
        }
      }
    }
  }
}

// ---------------- 8-phase 256x256 GEMM v2 (FF1): relu(A*BT^T + bias) --------
// Faithful two-barrier phase (m201 template): {stage issue | ds_read frags}
// -> s_barrier -> lgkmcnt(0)+sched_barrier -> setprio(1) 16 MFMA setprio(0)
// -> s_barrier. Counted vmcnt(6) once per K-tile (3 portions in flight).
// Staging machinery identical to r15 (proven bit-correct).
#define KG8_READB()                                                          \
  _Pragma("unroll") for (int ni = 0; ni < 4; ++ni)                           \
      _Pragma("unroll") for (int kk = 0; kk < 2; ++kk) {                     \
    int r = wc * 64 + ni * 16 + (l & 15);                                    \
    int s = (kk * 4 + (l >> 4)) ^ (r & 7);                                   \
    bfr[ni][kk] = *(const bf16x8*)&sB[cur][(r * 8 + s) * 8];                 \
  }
#define KG8_PHASE2(qq)                                                       \
  {                                                                          \
    bf16x8 afr[2][2];                                                        \
    _Pragma("unroll") for (int mi = 0; mi < 2; ++mi)                         \
        _Pragma("unroll") for (int kk = 0; kk < 2; ++kk) {                   \
      int r = wr * 128 + (qq)*32 + mi * 16 + (l & 15);                       \
      int s = (kk * 4 + (l >> 4)) ^ (r & 7);                                 \
      afr[mi][kk] = *(const bf16x8*)&sA[cur][(r * 8 + s) * 8];               \
    }                                                                        \
    __builtin_amdgcn_s_barrier();                                            \
    asm volatile("s_waitcnt lgkmcnt(0)" ::: "memory");                       \
    __builtin_amdgcn_sched_barrier(0);                                       \
    __builtin_amdgcn_s_setprio(1);                                           \
    _Pragma("unroll") for (int kk = 0; kk < 2; ++kk)                         \
        _Pragma("unroll") for (int mi = 0; mi < 2; ++mi)                     \
            _Pragma("unroll") for (int ni = 0; ni < 4; ++ni)                 \
                acc[(qq)*2 + mi][ni] =                                       \
                    __builtin_amdgcn_mfma_f32_16x16x32_bf16(                 \
                        afr[mi][kk], bfr[ni][kk], acc[(qq)*2 + mi][ni],      \
                        0, 0, 0);                                            \
    __builtin_amdgcn_s_setprio(0);                                           \
    __builtin_amdgcn_sched_barrier(0);                                       \
  }

__global__ __launch_bounds__(512, 2) void kgemm8(const u16* __restrict__ A,
                                                 const u16* __restrict__ BT,
                                                 int K,
                                                 const float* __restrict__ bias,
                                                 u16* __restrict__ out, int ldc) {
  __shared__ __align__(16) u16 sA[2][256 * 64];
  __shared__ __align__(16) u16 sB[2][256 * 64];
  int tid = threadIdx.x;
  int w = tid >> 6, l = tid & 63;
  int wr = w >> 2, wc = w & 3;
  // XCD-chunked swizzle (512 blocks % 8 == 0)
  int flat = blockIdx.y * gridDim.x + blockIdx.x;
  int cpx = (gridDim.x * gridDim.y) >> 3;
  int lg = (flat & 7) * cpx + (flat >> 3);
  int bx = lg % gridDim.x, by = lg / gridDim.x;
  long m0 = (long)by * 256, n0 = (long)bx * 256;
  const u16* Ab = A + m0 * K;
  const u16* Bb = BT + n0 * K;
  int nt = K >> 6;
  f32x4 acc[8][4] = {};

  auto stageA = [&](int b, int t, int p) {
    int ri = tid >> 3;
    int r = (ri < 32) ? (p * 32 + ri) : (128 + p * 32 + (ri - 32));
    int s = tid & 7;
    int k8 = s ^ (r & 7);
    int chunk = (ri < 32) ? (p * 256 + tid) : (1024 + p * 256 + (tid - 256));
    gld_lds16(Ab + (long)r * K + t * 64 + k8 * 8, &sA[b][chunk * 8]);
  };
  auto stageB = [&](int b, int t, int p) {
    int r = p * 64 + (tid >> 3);
    int s = tid & 7;
    int k8 = s ^ (r & 7);
    gld_lds16(Bb + (long)r * K + t * 64 + k8 * 8, &sB[b][(p * 512 + tid) * 8]);
  };

  // prologue: tile 0 fully (8 stages), tile 1 portions 0-2 (6 stages)
#pragma unroll
  for (int p = 0; p < 4; ++p) { stageA(0, 0, p); stageB(0, 0, p); }
#pragma unroll
  for (int p = 0; p < 3; ++p) { stageA(1, 1, p); stageB(1, 1, p); }
  asm volatile("s_waitcnt vmcnt(6)" ::: "memory");  // tile 0 landed
  __builtin_amdgcn_s_barrier();

  for (int t = 0; t + 2 < nt; ++t) {
    const int cur = t & 1;
    const int nxt = cur ^ 1;
    bf16x8 bfr[4][2];
    // phase 0: finish tile t+1 (portion 3 -> buf nxt); B-frags + quadrant 0
    stageA(nxt, t + 1, 3);
    stageB(nxt, t + 1, 3);
    KG8_READB();
    KG8_PHASE2(0);
    __builtin_amdgcn_s_barrier();
    // phase 1: stage t+2 portion 0 into buf cur (freed by phase 0)
    stageA(cur, t + 2, 0);
    stageB(cur, t + 2, 0);
    KG8_PHASE2(1);
    __builtin_amdgcn_s_barrier();
    // phase 2
    stageA(cur, t + 2, 1);
    stageB(cur, t + 2, 1);
    KG8_PHASE2(2);
    __builtin_amdgcn_s_barrier();
    // phase 3: counted wait -> tile t+1 fully landed (6 = t+2 stages in flight)
    stageA(cur, t + 2, 2);
    stageB(cur, t + 2, 2);
    KG8_PHASE2(3);
    asm volatile("s_waitcnt vmcnt(6)" ::: "memory");
    __builtin_amdgcn_s_barrier();
  }
  // peeled iter nt-2: finish tile nt-1 staging, compute tile nt-2
  {
    const int cur = (nt - 2) & 1;
    const int nxt = cur ^ 1;
    stageA(nxt, nt - 1, 3);
    stageB(nxt, nt - 1, 3);
    bf16x8 bfr[4][2];
    KG8_READB();
    KG8_PHASE2(0);
    __builtin_amdgcn_s_barrier();
    KG8_PHASE2(1);
    __builtin_amdgcn_s_barrier();
    KG8_PHASE2(2);
    __builtin_amdgcn_s_barrier();
    KG8_PHASE2(3);
    asm volatile("s_waitcnt vmcnt(0)" ::: "memory");  // tile nt-1 landed
    __builtin_amdgcn_s_barrier();
  }
  // peeled iter nt-1: compute last tile
  {
    const int cur = (nt - 1) & 1;
    bf16x8 bfr[4][2];
    KG8_READB();
    KG8_PHASE2(0);
    __builtin_amdgcn_s_barrier();
    KG8_PHASE2(1);
    __builtin_amdgcn_s_barrier();
    KG8_PHASE2(2);
    __builtin_amdgcn_s_barrier();
    KG8_PHASE2(3);
  }
  // epilogue: +bias, ReLU, bf16
#pragma unroll
  for (int m8 = 0; m8 < 8; ++m8) {
#pragma unroll
    for (int ni = 0; ni < 4; ++ni) {
#pragma unroll
      for (int j = 0; j < 4; ++j) {
        long row = m0 + wr * 128 + m8 * 16 + (l >> 4) * 4 + j;
        long col = n0 + wc * 64 + ni * 16 + (l & 15);
        float v = acc[m8][ni][j] + bias[col];
        v = fmaxf(v, 0.0f);
        out[row * (long)ldc + col] = f2bf(v);
      }
    }
  }
}

// ---------------- causal flash attention, swapped QK^T + defer-max ----------
__global__ __launch_bounds__(256) void kattn(const u16* __restrict__ q,
                                             const u16* __restrict__ kmat,
                                             const u16* __restrict__ vt,
                                             u16* __restrict__ o) {
  __shared__ __align__(16) u16 Ks[64 * 64];
  __shared__ __align__(16) u16 Vs[64 * 64];
  __shared__ __align__(16) u16 Ps[4 * 32 * 64];
  int bh = blockIdx.x;
  int qi = (gridDim.y - 1) - blockIdx.y;  // heavy q-tiles first
  int tid = threadIdx.x, w = tid >> 6, l = tid & 63;
  long bQ = (long)bh * 2048 * 64;
  int qrow0 = qi * 128 + w * 32;
  const float NEGINF = -__builtin_inff();

  bf16x8 qf[2][2];
#pragma unroll
  for (int mi = 0; mi < 2; ++mi)
#pragma unroll
    for (int kk = 0; kk < 2; ++kk) {
      int tt = qrow0 + mi * 16 + (l & 15);
      int kd = kk * 32 + (l >> 4) * 8;
      qf[mi][kk] = *(const bf16x8*)&q[bQ + (long)tt * 64 + kd];
    }
  f32x4 ao[2][4] = {};
  float mr[2] = {NEGINF, NEGINF}, lr[2] = {0.f, 0.f};

  u16* Pw = &Ps[w * 2048];
  int g = l >> 4;
  int njt = qi * 2 + 2;
  for (int jt = 0; jt < njt; ++jt) {
    int s0 = jt * 64;
    bool skip = (s0 > qrow0 + 31);
    bool need_mask = (s0 + 63 > qrow0);
    __syncthreads();
#pragma unroll
    for (int it = 0; it < 2; ++it) {
      int c = it * 256 + tid;
      int r = c >> 3;
      int k8 = (c & 7) ^ (r & 7);
      gld_lds16(&kmat[bQ + (long)(s0 + r) * 64 + k8 * 8], &Ks[c * 8]);
    }
#pragma unroll
    for (int it = 0; it < 2; ++it) {
      int c = it * 256 + tid;
      int r = c >> 3;
      int s8 = (c & 7) ^ (r & 7);
      gld_lds16(&vt[bQ + (long)r * 2048 + s0 + s8 * 8], &Vs[c * 8]);
    }
    __syncthreads();
    if (skip) continue;
    f32x4 sc[2][4] = {};
#pragma unroll
    for (int kk = 0; kk < 2; ++kk) {
      int k8 = kk * 4 + g;
      bf16x8 kf[4];
#pragma unroll
      for (int ni = 0; ni < 4; ++ni) {
        int r = ni * 16 + (l & 15);
        kf[ni] = *(const bf16x8*)&Ks[(r * 8 + (k8 ^ (r & 7))) * 8];
      }
#pragma unroll
      for (int mi = 0; mi < 2; ++mi)
#pragma unroll
        for (int ni = 0; ni < 4; ++ni)
          sc[mi][ni] =
              __builtin_amdgcn_mfma_f32_16x16x32_bf16(kf[ni], qf[mi][kk], sc[mi][ni], 0, 0, 0);
    }
#pragma unroll
    for (int mi = 0; mi < 2; ++mi) {
      float rmax = NEGINF;
      if (need_mask) {
        int tg = qrow0 + mi * 16 + (l & 15);
#pragma unroll
        for (int ni = 0; ni < 4; ++ni)
#pragma unroll
          for (int j = 0; j < 4; ++j) {
            int sg = s0 + ni * 16 + g * 4 + j;
            float vv = sc[mi][ni][j];
            vv = (sg <= tg) ? vv : NEGINF;
            sc[mi][ni][j] = vv;
            rmax = fmaxf(rmax, vv);
          }
      } else {
#pragma unroll
        for (int ni = 0; ni < 4; ++ni)
#pragma unroll
          for (int j = 0; j < 4; ++j) rmax = fmaxf(rmax, sc[mi][ni][j]);
      }
      rmax = fmaxf(rmax, __shfl_xor(rmax, 16));
      rmax = fmaxf(rmax, __shfl_xor(rmax, 32));
      if (!__all(rmax <= mr[mi] + 11.5f)) {
        float mnew = fmaxf(mr[mi], rmax);
        float alpha = fexp2(mr[mi] - mnew);
        mr[mi] = mnew;
        lr[mi] *= alpha;
#pragma unroll
        for (int j = 0; j < 4; ++j) {
          float at = __shfl(alpha, g * 4 + j);
#pragma unroll
          for (int nd = 0; nd < 4; ++nd) ao[mi][nd][j] *= at;
        }
      }
      float rsum = 0.f;
#pragma unroll
      for (int ni = 0; ni < 4; ++ni)
#pragma unroll
        for (int j = 0; j < 4; ++j) {
          float p = fexp2(sc[mi][ni][j] - mr[mi]);
          sc[mi][ni][j] = p;
          rsum += p;
        }
      rsum += __shfl_xor(rsum, 16);
      rsum += __shfl_xor(rsum, 32);
      lr[mi] += rsum;
    }
#pragma unroll
    for (int mi = 0; mi < 2; ++mi) {
      int r = mi * 16 + (l & 15);
#pragma unroll
      for (int ni = 0; ni < 4; ++ni) {
        int cc0 = ni * 16 + g * 4;
        int addr = (r * 8 + ((cc0 >> 3) ^ (r & 7))) * 8 + (cc0 & 7);
        u16 h4[4] = {f2bf(sc[mi][ni][0]), f2bf(sc[mi][ni][1]),
                     f2bf(sc[mi][ni][2]), f2bf(sc[mi][ni][3])};
        *(uint2*)&Pw[addr] = *(uint2*)h4;
      }
    }
#pragma unroll
    for (int kk = 0; kk < 2; ++kk) {
      int s8 = kk * 4 + g;
      bf16x8 pf[2], vf[4];
#pragma unroll
      for (int mi = 0; mi < 2; ++mi) {
        int r = mi * 16 + (l & 15);
        pf[mi] = *(const bf16x8*)&Pw[(r * 8 + (s8 ^ (r & 7))) * 8];
      }
#pragma unroll
      for (int nd = 0; nd < 4; ++nd) {
        int r = nd * 16 + (l & 15);
        vf[nd] = *(const bf16x8*)&Vs[(r * 8 + (s8 ^ (r & 7))) * 8];
      }
#pragma unroll
      for (int mi = 0; mi < 2; ++mi)
#pragma unroll
        for (int nd = 0; nd < 4; ++nd)
          ao[mi][nd] =
              __builtin_amdgcn_mfma_f32_16x16x32_bf16(pf[mi], vf[nd], ao[mi][nd], 0, 0, 0);
    }
  }
  int b = bh >> 4, h = bh & 15;
#pragma unroll
  for (int mi = 0; mi < 2; ++mi) {
#pragma unroll
    for (int j = 0; j < 4; ++j) {
      float lrt = __shfl(lr[mi], g * 4 + j);
      float rinv = 1.0f / lrt;
#pragma unroll
      for (int nd = 0; nd < 4; ++nd) {
        int tt = qrow0 + mi * 16 + g * 4 + j;
        int dd = nd * 16 + (l & 15);
        o[((long)(b * 2048 + tt)) * 1024 + h * 64 + dd] = f2bf(ao[mi][nd][j] * rinv);
      }
    }
  }
}

// ---------------- launch -----------------------------------------------------
extern "C" void kernel_launch(void* const* d_in, const int* in_sizes, int n_in,
                              void* d_out, int out_size, void* d_ws, size_t ws_size,
                              hipStream_t stream) {
  const float* x = (const float*)d_in[0];
  const float* Wq = (const float*)d_in[1];
  const float* Wk = (const float*)d_in[2];
  const float* Wv = (const float*)d_in[3];
  const float* Wp = (const float*)d_in[4];
  const float* bp = (const float*)d_in[5];
  const float* W1 = (const float*)d_in[6];
  const float* b1 = (const float*)d_in[7];
  const float* W2 = (const float*)d_in[8];
  const float* b2 = (const float*)d_in[9];
  const float* g1 = (const float*)d_in[10];
  const float* be1 = (const float*)d_in[11];
  const float* g2 = (const float*)d_in[12];
  const float* be2 = (const float*)d_in[13];

  u16* ws = (u16*)d_ws;
  u16* wqkvT = ws;                    // [3072,1024] bf16 (q, k, v blocks)
  u16* wpT = wqkvT + 3145728;         // [1024,1024]
  u16* w1T = wpT + 1048576;           // [4096,1024]
  u16* w2T = w1T + 4194304;           // [1024,4096]
  u16* qb = w2T + 4194304;            // [B,H,T,64] (q) + [B,H,T,64] (k)
  u16* kb = qb + 8388608;
  u16* vb = kb + 8388608;             // scratch slab (x2 lives here)
  u16* vtb = vb + 8388608;            // [B*H,64,T]  (V written transposed)
  u16* ob = vtb + 8388608;            // [B,T,C]
  u16* x1 = ob + 8388608;             // [B,T,C]
  float* outp = (float*)d_out;        // fp32 (reference output dtype)
  u16* x2 = vb;    // scratch slab
  u16* x3 = ob;    // o dead after proj
  u16* hb = qb;    // FF hidden [8192,4096] spans qb..vtb (all dead by FF1)

  // merged prep: LN1 + all weight transposes in ONE dispatch
  kprep<<<11264, 256, 0, stream>>>(x, Wq, Wk, Wv, Wp, W1, W2, g1, be1,
                                   x1, wqkvT, wpT, w1T, w2T);

  kgemm<0, 0><<<dim3(24, 64), 256, 0, stream>>>(x1, wqkvT, 1024, nullptr, nullptr, qb, 0, vtb);
  kattn<<<dim3(64, 16), 256, 0, stream>>>(qb, kb, vtb, ob);
  kgemm<1, 0><<<dim3(8, 64), 256, 0, stream>>>(ob, wpT, 1024, bp, x1, x2, 1024, nullptr);
  kln_b<<<8192, 256, 0, stream>>>(x2, g2, be2, x3);
  kgemm8<<<dim3(16, 32), 512, 0, stream>>>(x3, w1T, 1024, b1, hb, 4096);
  kgemm<1, 1><<<dim3(8, 64), 256, 0, stream>>>(hb, w2T, 4096, b2, x3, outp, 1024, nullptr);
}

// Round 22
// 389.217 us; speedup vs baseline: 1.0191x; 1.0191x over previous
//
#include <hip/hip_runtime.h>
#include <cstdint>

typedef unsigned short u16;
typedef unsigned int u32;
typedef __bf16 bf16x8 __attribute__((ext_vector_type(8)));
typedef float f32x4 __attribute__((ext_vector_type(4)));

#define DEVINL __device__ __forceinline__

DEVINL float bf2f(u16 h) { union { u32 u; float f; } v; v.u = ((u32)h) << 16; return v.f; }
DEVINL u16 f2bf(float f) {
  union { __bf16 h; u16 u; } v;
  v.h = (__bf16)f;  // native cvt (RNE); pairs into v_cvt_pk_bf16_f32
  return v.u;
}

DEVINL float fexp2(float x) {
#if __has_builtin(__builtin_amdgcn_exp2f)
  return __builtin_amdgcn_exp2f(x);
#else
  return exp2f(x);
#endif
}

// async global->LDS, 16B per lane. LDS dest must be wave-uniform base + lane*16.
DEVINL void gld_lds16(const void* g, void* l) {
  __builtin_amdgcn_global_load_lds(
      (__attribute__((address_space(1))) void*)(g),
      (__attribute__((address_space(3))) void*)(l), 16, 0, 0);
}

// ---------------- merged prep: LN1 (blocks 0..8191) + 6 weight transposes ---
__global__ __launch_bounds__(256) void kprep(
    const float* __restrict__ x, const float* __restrict__ Wq,
    const float* __restrict__ Wk, const float* __restrict__ Wv,
    const float* __restrict__ Wp, const float* __restrict__ W1,
    const float* __restrict__ W2, const float* __restrict__ g,
    const float* __restrict__ be, u16* __restrict__ x1,
    u16* __restrict__ wqkvT, u16* __restrict__ wpT,
    u16* __restrict__ w1T, u16* __restrict__ w2T) {
  int b = blockIdx.x;
  int t = threadIdx.x;
  if (b < 8192) {  // ---- LN1 row b (fp32 input) ----
    long row = b;
    float4 xv = *(const float4*)&x[row * 1024 + t * 4];
    float f0 = xv.x, f1 = xv.y, f2 = xv.z, f3 = xv.w;
    float s = f0 + f1 + f2 + f3;
    float s2 = f0 * f0 + f1 * f1 + f2 * f2 + f3 * f3;
#pragma unroll
    for (int off = 32; off >= 1; off >>= 1) {
      s += __shfl_xor(s, off);
      s2 += __shfl_xor(s2, off);
    }
    __shared__ float red[8];
    int w = t >> 6, l = t & 63;
    if (l == 0) { red[w] = s; red[4 + w] = s2; }
    __syncthreads();
    s = red[0] + red[1] + red[2] + red[3];
    s2 = red[4] + red[5] + red[6] + red[7];
    float mu = s * (1.0f / 1024.0f);
    float var = s2 * (1.0f / 1024.0f) - mu * mu;
    float rs = rsqrtf(var + 1e-5f);
    float4 gv = *(const float4*)&g[t * 4];
    float4 bv = *(const float4*)&be[t * 4];
    ushort4 ov;
    ov.x = f2bf((f0 - mu) * rs * gv.x + bv.x);
    ov.y = f2bf((f1 - mu) * rs * gv.y + bv.y);
    ov.z = f2bf((f2 - mu) * rs * gv.z + bv.z);
    ov.w = f2bf((f3 - mu) * rs * gv.w + bv.w);
    *(ushort4*)&x1[row * 1024 + t * 4] = ov;
    return;
  }
  int jb = b - 8192;
  const float* in;
  u16* out;
  int R, C, c0, r0;
  if (jb < 768) {
    int which = jb >> 8;
    int idx = jb & 255;
    int z = idx >> 4, y = idx & 15;
    const float* W = (which == 0) ? Wq : ((which == 1) ? Wk : Wv);
    in = W + (long)z * 65536;
    out = wqkvT + (long)which * 1048576 + (long)z * 65536;
    R = 1024; C = 64; c0 = 0; r0 = y * 64;
  } else if (jb < 1024) {
    int idx = jb - 768;
    in = Wp; out = wpT; R = 1024; C = 1024;
    c0 = (idx & 15) * 64; r0 = (idx >> 4) * 64;
  } else if (jb < 2048) {
    int idx = jb - 1024;
    in = W1; out = w1T; R = 1024; C = 4096;
    c0 = (idx & 63) * 64; r0 = (idx >> 6) * 64;
  } else {
    int idx = jb - 2048;
    in = W2; out = w2T; R = 4096; C = 1024;
    c0 = (idx & 15) * 64; r0 = (idx >> 4) * 64;
  }
  __shared__ __align__(16) u16 tile[64][80];
#pragma unroll
  for (int ph = 0; ph < 2; ++ph) {
    int ch = ph * 256 + t;
    int r = ch >> 3, cc = (ch & 7) * 8;
    const float* src = &in[(long)(r0 + r) * C + c0 + cc];
    float4 a = *(const float4*)src;
    float4 bb = *(const float4*)(src + 4);
    u16 tmp[8] = {f2bf(a.x), f2bf(a.y), f2bf(a.z), f2bf(a.w),
                  f2bf(bb.x), f2bf(bb.y), f2bf(bb.z), f2bf(bb.w)};
    *(uint4*)&tile[r][cc] = *(uint4*)tmp;
  }
  __syncthreads();
#pragma unroll
  for (int ph = 0; ph < 2; ++ph) {
    int ch = ph * 256 + t;
    int c = ch >> 3, rr = (ch & 7) * 8;
    u16 tmp[8];
#pragma unroll
    for (int i = 0; i < 8; ++i) tmp[i] = tile[rr + i][c];
    *(uint4*)&out[(long)(c0 + c) * R + r0 + rr] = *(uint4*)tmp;
  }
}

// -------- LayerNorm rows of 1024, bf16 input --------------------------------
__global__ __launch_bounds__(256) void kln_b(const u16* __restrict__ x,
                                             const float* __restrict__ g,
                                             const float* __restrict__ be,
                                             u16* __restrict__ y) {
  long row = blockIdx.x;
  int t = threadIdx.x;
  ushort4 xv = *(const ushort4*)&x[row * 1024 + t * 4];
  float f0 = bf2f(xv.x), f1 = bf2f(xv.y), f2 = bf2f(xv.z), f3 = bf2f(xv.w);
  float s = f0 + f1 + f2 + f3;
  float s2 = f0 * f0 + f1 * f1 + f2 * f2 + f3 * f3;
#pragma unroll
  for (int off = 32; off >= 1; off >>= 1) {
    s += __shfl_xor(s, off);
    s2 += __shfl_xor(s2, off);
  }
  __shared__ float red[8];
  int w = t >> 6, l = t & 63;
  if (l == 0) { red[w] = s; red[4 + w] = s2; }
  __syncthreads();
  s = red[0] + red[1] + red[2] + red[3];
  s2 = red[4] + red[5] + red[6] + red[7];
  float mu = s * (1.0f / 1024.0f);
  float var = s2 * (1.0f / 1024.0f) - mu * mu;
  float rs = rsqrtf(var + 1e-5f);
  float4 gv = *(const float4*)&g[t * 4];
  float4 bv = *(const float4*)&be[t * 4];
  ushort4 ov;
  ov.x = f2bf((f0 - mu) * rs * gv.x + bv.x);
  ov.y = f2bf((f1 - mu) * rs * gv.y + bv.y);
  ov.z = f2bf((f2 - mu) * rs * gv.z + bv.z);
  ov.w = f2bf((f3 - mu) * rs * gv.w + bv.w);
  *(ushort4*)&y[row * 1024 + t * 4] = ov;
}

// ---------------- GEMM (r17 proven 128x128 structure + XCD swizzle) ---------
template <int EPI, int OF32>
__global__ __launch_bounds__(256) void kgemm(const u16* __restrict__ A,
                                             const u16* __restrict__ BT, int K,
                                             const float* __restrict__ bias,
                                             const u16* __restrict__ resid,
                                             void* __restrict__ outv, int ldc,
                                             u16* __restrict__ vout) {
  __shared__ __align__(16) u16 sA[128 * 64];
  __shared__ __align__(16) u16 sB[128 * 64];
  int tid = threadIdx.x;
  int l = tid & 63, wv = tid >> 6;
  int wm = (wv >> 1) * 64, wn = (wv & 1) * 64;
  int flat = blockIdx.y * gridDim.x + blockIdx.x;
  int cpx = (gridDim.x * gridDim.y) >> 3;
  int lg = (flat & 7) * cpx + (flat >> 3);
  int bx = lg % gridDim.x, by = lg / gridDim.x;
  long m0 = (long)by * 128, n0 = (long)bx * 128;
  const u16* Ab = A + m0 * K;
  const u16* Bb = BT + n0 * K;
  f32x4 acc[4][4] = {};

  for (int k0 = 0; k0 < K; k0 += 64) {
    __syncthreads();
#pragma unroll
    for (int it = 0; it < 4; ++it) {
      int c = it * 256 + tid;
      int r = c >> 3;
      int k8 = (c & 7) ^ (r & 7);
      gld_lds16(Ab + (long)r * K + k0 + k8 * 8, &sA[c * 8]);
    }
#pragma unroll
    for (int it = 0; it < 4; ++it) {
      int c = it * 256 + tid;
      int r = c >> 3;
      int k8 = (c & 7) ^ (r & 7);
      gld_lds16(Bb + (long)r * K + k0 + k8 * 8, &sB[c * 8]);
    }
    __syncthreads();
#pragma unroll
    for (int kk = 0; kk < 2; ++kk) {
      int k8 = kk * 4 + (l >> 4);
      bf16x8 af[4], bfr[4];
#pragma unroll
      for (int mi = 0; mi < 4; ++mi) {
        int r = wm + mi * 16 + (l & 15);
        af[mi] = *(const bf16x8*)&sA[(r * 8 + (k8 ^ (r & 7))) * 8];
      }
#pragma unroll
      for (int ni = 0; ni < 4; ++ni) {
        int r = wn + ni * 16 + (l & 15);
        bfr[ni] = *(const bf16x8*)&sB[(r * 8 + (k8 ^ (r & 7))) * 8];
      }
#pragma unroll
      for (int mi = 0; mi < 4; ++mi)
#pragma unroll
        for (int ni = 0; ni < 4; ++ni)
          acc[mi][ni] =
              __builtin_amdgcn_mfma_f32_16x16x32_bf16(af[mi], bfr[ni], acc[mi][ni], 0, 0, 0);
    }
  }
#pragma unroll
  for (int mi = 0; mi < 4; ++mi) {
#pragma unroll
    for (int ni = 0; ni < 4; ++ni) {
#pragma unroll
      for (int j = 0; j < 4; ++j) {
        long row = m0 + wm + mi * 16 + (l >> 4) * 4 + j;
        long col = n0 + wn + ni * 16 + (l & 15);
        float v = acc[mi][ni][j];
        if constexpr (EPI == 0) {
          long tn = col >> 10, jj = col & 1023;
          long hh = jj >> 6, dd = jj & 63;
          long bb = row >> 11, tt = row & 2047;
          if (tn == 0) {
            v *= 0.045084220027780106f;  // log2(e)/32: exp2 domain
            ((u16*)outv)[(((bb)*16 + hh) * 2048 + tt) * 64 + dd] = f2bf(v);
          } else if (tn == 1) {
            ((u16*)outv)[(((4 + bb) * 16 + hh) * 2048 + tt) * 64 + dd] = f2bf(v);
          } else {  // V: write directly transposed [bh][d][T]
            vout[((bb * 16 + hh) * 64 + dd) * 2048 + tt] = f2bf(v);
          }
        } else {
          v += bias[col];
          if constexpr (EPI == 2) v = fmaxf(v, 0.0f);
          if constexpr (EPI == 1) v += bf2f(resid[row * ldc + col]);
          if constexpr (OF32) ((float*)outv)[row * ldc + col] = v;
          else ((u16*)outv)[row * ldc + col] = f2bf(v);
        }
      }
    }
  }
}

// ---------------- causal flash attention, swapped QK^T + defer-max ----------
__global__ __launch_bounds__(256) void kattn(const u16* __restrict__ q,
                                             const u16* __restrict__ kmat,
                                             const u16* __restrict__ vt,
                                             u16* __restrict__ o) {
  __shared__ __align__(16) u16 Ks[64 * 64];
  __shared__ __align__(16) u16 Vs[64 * 64];
  __shared__ __align__(16) u16 Ps[4 * 32 * 64];
  int bh = blockIdx.x;
  int qi = (gridDim.y - 1) - blockIdx.y;  // heavy q-tiles first
  int tid = threadIdx.x, w = tid >> 6, l = tid & 63;
  long bQ = (long)bh * 2048 * 64;
  int qrow0 = qi * 128 + w * 32;
  const float NEGINF = -__builtin_inff();

  bf16x8 qf[2][2];
#pragma unroll
  for (int mi = 0; mi < 2; ++mi)
#pragma unroll
    for (int kk = 0; kk < 2; ++kk) {
      int tt = qrow0 + mi * 16 + (l & 15);
      int kd = kk * 32 + (l >> 4) * 8;
      qf[mi][kk] = *(const bf16x8*)&q[bQ + (long)tt * 64 + kd];
    }
  f32x4 ao[2][4] = {};
  float mr[2] = {NEGINF, NEGINF}, lr[2] = {0.f, 0.f};

  u16* Pw = &Ps[w * 2048];
  int g = l >> 4;
  int njt = qi * 2 + 2;
  for (int jt = 0; jt < njt; ++jt) {
    int s0 = jt * 64;
    bool skip = (s0 > qrow0 + 31);
    bool need_mask = (s0 + 63 > qrow0);
    __syncthreads();
#pragma unroll
    for (int it = 0; it < 2; ++it) {
      int c = it * 256 + tid;
      int r = c >> 3;
      int k8 = (c & 7) ^ (r & 7);
      gld_lds16(&kmat[bQ + (long)(s0 + r) * 64 + k8 * 8], &Ks[c * 8]);
    }
#pragma unroll
    for (int it = 0; it < 2; ++it) {
      int c = it * 256 + tid;
      int r = c >> 3;
      int s8 = (c & 7) ^ (r & 7);
      gld_lds16(&vt[bQ + (long)r * 2048 + s0 + s8 * 8], &Vs[c * 8]);
    }
    __syncthreads();
    if (skip) continue;
    f32x4 sc[2][4] = {};
#pragma unroll
    for (int kk = 0; kk < 2; ++kk) {
      int k8 = kk * 4 + g;
      bf16x8 kf[4];
#pragma unroll
      for (int ni = 0; ni < 4; ++ni) {
        int r = ni * 16 + (l & 15);
        kf[ni] = *(const bf16x8*)&Ks[(r * 8 + (k8 ^ (r & 7))) * 8];
      }
#pragma unroll
      for (int mi = 0; mi < 2; ++mi)
#pragma unroll
        for (int ni = 0; ni < 4; ++ni)
          sc[mi][ni] =
              __builtin_amdgcn_mfma_f32_16x16x32_bf16(kf[ni], qf[mi][kk], sc[mi][ni], 0, 0, 0);
    }
#pragma unroll
    for (int mi = 0; mi < 2; ++mi) {
      float rmax = NEGINF;
      if (need_mask) {
        int tg = qrow0 + mi * 16 + (l & 15);
#pragma unroll
        for (int ni = 0; ni < 4; ++ni)
#pragma unroll
          for (int j = 0; j < 4; ++j) {
            int sg = s0 + ni * 16 + g * 4 + j;
            float vv = sc[mi][ni][j];
            vv = (sg <= tg) ? vv : NEGINF;
            sc[mi][ni][j] = vv;
            rmax = fmaxf(rmax, vv);
          }
      } else {
#pragma unroll
        for (int ni = 0; ni < 4; ++ni)
#pragma unroll
          for (int j = 0; j < 4; ++j) rmax = fmaxf(rmax, sc[mi][ni][j]);
      }
      rmax = fmaxf(rmax, __shfl_xor(rmax, 16));
      rmax = fmaxf(rmax, __shfl_xor(rmax, 32));
      if (!__all(rmax <= mr[mi] + 11.5f)) {
        float mnew = fmaxf(mr[mi], rmax);
        float alpha = fexp2(mr[mi] - mnew);
        mr[mi] = mnew;
        lr[mi] *= alpha;
#pragma unroll
        for (int j = 0; j < 4; ++j) {
          float at = __shfl(alpha, g * 4 + j);
#pragma unroll
          for (int nd = 0; nd < 4; ++nd) ao[mi][nd][j] *= at;
        }
      }
      float rsum = 0.f;
#pragma unroll
      for (int ni = 0; ni < 4; ++ni)
#pragma unroll
        for (int j = 0; j < 4; ++j) {
          float p = fexp2(sc[mi][ni][j] - mr[mi]);
          sc[mi][ni][j] = p;
          rsum += p;
        }
      rsum += __shfl_xor(rsum, 16);
      rsum += __shfl_xor(rsum, 32);
      lr[mi] += rsum;
    }
#pragma unroll
    for (int mi = 0; mi < 2; ++mi) {
      int r = mi * 16 + (l & 15);
#pragma unroll
      for (int ni = 0; ni < 4; ++ni) {
        int cc0 = ni * 16 + g * 4;
        int addr = (r * 8 + ((cc0 >> 3) ^ (r & 7))) * 8 + (cc0 & 7);
        u16 h4[4] = {f2bf(sc[mi][ni][0]), f2bf(sc[mi][ni][1]),
                     f2bf(sc[mi][ni][2]), f2bf(sc[mi][ni][3])};
        *(uint2*)&Pw[addr] = *(uint2*)h4;
      }
    }
#pragma unroll
    for (int kk = 0; kk < 2; ++kk) {
      int s8 = kk * 4 + g;
      bf16x8 pf[2], vf[4];
#pragma unroll
      for (int mi = 0; mi < 2; ++mi) {
        int r = mi * 16 + (l & 15);
        pf[mi] = *(const bf16x8*)&Pw[(r * 8 + (s8 ^ (r & 7))) * 8];
      }
#pragma unroll
      for (int nd = 0; nd < 4; ++nd) {
        int r = nd * 16 + (l & 15);
        vf[nd] = *(const bf16x8*)&Vs[(r * 8 + (s8 ^ (r & 7))) * 8];
      }
#pragma unroll
      for (int mi = 0; mi < 2; ++mi)
#pragma unroll
        for (int nd = 0; nd < 4; ++nd)
          ao[mi][nd] =
              __builtin_amdgcn_mfma_f32_16x16x32_bf16(pf[mi], vf[nd], ao[mi][nd], 0, 0, 0);
    }
  }
  int b = bh >> 4, h = bh & 15;
#pragma unroll
  for (int mi = 0; mi < 2; ++mi) {
#pragma unroll
    for (int j = 0; j < 4; ++j) {
      float lrt = __shfl(lr[mi], g * 4 + j);
      float rinv = 1.0f / lrt;
#pragma unroll
      for (int nd = 0; nd < 4; ++nd) {
        int tt = qrow0 + mi * 16 + g * 4 + j;
        int dd = nd * 16 + (l & 15);
        o[((long)(b * 2048 + tt)) * 1024 + h * 64 + dd] = f2bf(ao[mi][nd][j] * rinv);
      }
    }
  }
}

// ---------------- launch -----------------------------------------------------
extern "C" void kernel_launch(void* const* d_in, const int* in_sizes, int n_in,
                              void* d_out, int out_size, void* d_ws, size_t ws_size,
                              hipStream_t stream) {
  const float* x = (const float*)d_in[0];
  const float* Wq = (const float*)d_in[1];
  const float* Wk = (const float*)d_in[2];
  const float* Wv = (const float*)d_in[3];
  const float* Wp = (const float*)d_in[4];
  const float* bp = (const float*)d_in[5];
  const float* W1 = (const float*)d_in[6];
  const float* b1 = (const float*)d_in[7];
  const float* W2 = (const float*)d_in[8];
  const float* b2 = (const float*)d_in[9];
  const float* g1 = (const float*)d_in[10];
  const float* be1 = (const float*)d_in[11];
  const float* g2 = (const float*)d_in[12];
  const float* be2 = (const float*)d_in[13];

  u16* ws = (u16*)d_ws;
  u16* wqkvT = ws;                    // [3072,1024] bf16 (q, k, v blocks)
  u16* wpT = wqkvT + 3145728;         // [1024,1024]
  u16* w1T = wpT + 1048576;           // [4096,1024]
  u16* w2T = w1T + 4194304;           // [1024,4096]
  u16* qb = w2T + 4194304;            // [B,H,T,64] (q) + [B,H,T,64] (k)
  u16* kb = qb + 8388608;
  u16* vb = kb + 8388608;             // scratch slab (x2 lives here)
  u16* vtb = vb + 8388608;            // [B*H,64,T]  (V written transposed)
  u16* ob = vtb + 8388608;            // [B,T,C]
  u16* x1 = ob + 8388608;             // [B,T,C]
  float* outp = (float*)d_out;        // fp32 (reference output dtype)
  u16* x2 = vb;    // scratch slab
  u16* x3 = ob;    // o dead after proj
  u16* hb = qb;    // FF hidden [8192,4096] spans qb..vtb (all dead by FF1)

  // merged prep: LN1 + all weight transposes in ONE dispatch
  kprep<<<11264, 256, 0, stream>>>(x, Wq, Wk, Wv, Wp, W1, W2, g1, be1,
                                   x1, wqkvT, wpT, w1T, w2T);

  kgemm<0, 0><<<dim3(24, 64), 256, 0, stream>>>(x1, wqkvT, 1024, nullptr, nullptr, qb, 0, vtb);
  kattn<<<dim3(64, 16), 256, 0, stream>>>(qb, kb, vtb, ob);
  kgemm<1, 0><<<dim3(8, 64), 256, 0, stream>>>(ob, wpT, 1024, bp, x1, x2, 1024, nullptr);
  kln_b<<<8192, 256, 0, stream>>>(x2, g2, be2, x3);
  kgemm<2, 0><<<dim3(32, 64), 256, 0, stream>>>(x3, w1T, 1024, b1, nullptr, hb, 4096, nullptr);
  kgemm<1, 1><<<dim3(8, 64), 256, 0, stream>>>(hb, w2T, 4096, b2, x3, outp, 1024, nullptr);
}